// Round 1
// baseline (1093.100 us; speedup 1.0000x reference)
//
#include <hip/hip_runtime.h>
#include <hip/hip_bf16.h>
#include <stdint.h>

#define M_DIM 16384
#define N_DIM 4096
#define K_DIM 4096

typedef __attribute__((ext_vector_type(8))) short short8;   // 8 bf16 (4 VGPRs)
typedef __attribute__((ext_vector_type(4))) float f32x4;    // 4 fp32 acc

__device__ __forceinline__ unsigned short f32_bf16(float f) {
    union { float f; unsigned int u; } v; v.f = f;
    unsigned int u = v.u;
    unsigned int r = u + 0x7FFFu + ((u >> 16) & 1u);   // RNE
    return (unsigned short)(r >> 16);
}

// fp32 -> bf16, 8 elems/thread, exact grid (n % 2048 == 0)
__global__ __launch_bounds__(256) void cvt_f32_to_bf16(
        const float* __restrict__ src, unsigned short* __restrict__ dst) {
    size_t i = ((size_t)blockIdx.x * 256 + threadIdx.x) * 8;
    const float4* s = (const float4*)(src + i);
    float4 a = s[0];
    float4 b = s[1];
    uint4 o;
    o.x = (unsigned)f32_bf16(a.x) | ((unsigned)f32_bf16(a.y) << 16);
    o.y = (unsigned)f32_bf16(a.z) | ((unsigned)f32_bf16(a.w) << 16);
    o.z = (unsigned)f32_bf16(b.x) | ((unsigned)f32_bf16(b.y) << 16);
    o.w = (unsigned)f32_bf16(b.z) | ((unsigned)f32_bf16(b.w) << 16);
    *(uint4*)(dst + i) = o;
}

// C[M,N] = A[M,K] * B[N,K]^T + bias ; A,B bf16, C fp32.
// m97 structure: 128x128 tile, BK=32, 4 waves, 4x4 16x16x32 MFMAs/wave,
// global_load_lds width=16 staging, 2-barrier K-loop.
__global__ __launch_bounds__(256) void gemm_bt_bias(
        const unsigned short* __restrict__ A,
        const unsigned short* __restrict__ B,
        const float* __restrict__ bias,
        float* __restrict__ C) {
    __shared__ __align__(16) unsigned short sA[128 * 32];
    __shared__ __align__(16) unsigned short sB[128 * 32];

    const int tid  = threadIdx.x;
    const int wave = tid >> 6;
    const int lane = tid & 63;
    const int bm   = blockIdx.y;
    const int bn   = blockIdx.x;

    // staging: per call c (0..1), thread tid covers tile bytes c*4096 + tid*16
    // global row = c*64 + (tid>>2), cols (tid&3)*8 .. +7
    const int srow = tid >> 2;
    const int scol = (tid & 3) << 3;
    const unsigned short* gA = A + (size_t)(bm * 128 + srow) * K_DIM + scol;
    const unsigned short* gB = B + (size_t)(bn * 128 + srow) * K_DIM + scol;
    // LDS dest base must be wave-uniform; lane data lands at base + lane*16
    unsigned short* lA = sA + wave * 512;   // bytes: wave*1024
    unsigned short* lB = sB + wave * 512;

    const int wr   = (wave >> 1) << 6;      // wave row offset: 0 / 64
    const int wc   = (wave & 1) << 6;       // wave col offset: 0 / 64
    const int mrow = lane & 15;
    const int quad = lane >> 4;

    f32x4 acc[4][4] = {};

    for (int k0 = 0; k0 < K_DIM; k0 += 32) {
#pragma unroll
        for (int c = 0; c < 2; ++c) {
            __builtin_amdgcn_global_load_lds(
                (const __attribute__((address_space(1))) void*)(gA + (size_t)(c * 64) * K_DIM + k0),
                (__attribute__((address_space(3))) void*)(lA + c * 2048), 16, 0, 0);
            __builtin_amdgcn_global_load_lds(
                (const __attribute__((address_space(1))) void*)(gB + (size_t)(c * 64) * K_DIM + k0),
                (__attribute__((address_space(3))) void*)(lB + c * 2048), 16, 0, 0);
        }
        __syncthreads();   // drains vmcnt -> staged data visible

        short8 af[4], bfr[4];
#pragma unroll
        for (int i = 0; i < 4; ++i)
            af[i] = *(const short8*)(sA + (wr + i * 16 + mrow) * 32 + quad * 8);
#pragma unroll
        for (int j = 0; j < 4; ++j)
            bfr[j] = *(const short8*)(sB + (wc + j * 16 + mrow) * 32 + quad * 8);
#pragma unroll
        for (int i = 0; i < 4; ++i)
#pragma unroll
            for (int j = 0; j < 4; ++j)
                acc[i][j] = __builtin_amdgcn_mfma_f32_16x16x32_bf16(af[i], bfr[j], acc[i][j], 0, 0, 0);
        __syncthreads();   // all waves done reading before next stage
    }

    // epilogue: C/D layout col=lane&15, row=quad*4+reg
    float bv[4];
#pragma unroll
    for (int j = 0; j < 4; ++j)
        bv[j] = bias[bn * 128 + wc + j * 16 + mrow];

#pragma unroll
    for (int i = 0; i < 4; ++i) {
#pragma unroll
        for (int r = 0; r < 4; ++r) {
            int m = bm * 128 + wr + i * 16 + quad * 4 + r;
            float* crow = C + (size_t)m * N_DIM + bn * 128 + wc + mrow;
#pragma unroll
            for (int j = 0; j < 4; ++j)
                crow[j * 16] = acc[i][j][r] + bv[j];
        }
    }
}

extern "C" void kernel_launch(void* const* d_in, const int* in_sizes, int n_in,
                              void* d_out, int out_size, void* d_ws, size_t ws_size,
                              hipStream_t stream) {
    const float* x    = (const float*)d_in[0];   // [8,2048,4096] = [16384,4096]
    const float* w    = (const float*)d_in[1];   // [4096,4096]
    const float* bias = (const float*)d_in[2];   // [4096]
    float* out        = (float*)d_out;           // [16384,4096]

    // workspace: xb (128 MiB) + wb (32 MiB) = 160 MiB of d_ws
    unsigned short* xb = (unsigned short*)d_ws;
    unsigned short* wb = xb + (size_t)M_DIM * K_DIM;

    cvt_f32_to_bf16<<<(M_DIM * (size_t)K_DIM) / 2048, 256, 0, stream>>>(x, xb);
    cvt_f32_to_bf16<<<(N_DIM * (size_t)K_DIM) / 2048, 256, 0, stream>>>(w, wb);
    gemm_bt_bias<<<dim3(N_DIM / 128, M_DIM / 128), 256, 0, stream>>>(xb, wb, bias, out);
}